// Round 5
// baseline (1094.818 us; speedup 1.0000x reference)
//
#include <hip/hip_runtime.h>
#include <math.h>

constexpr int FDIM = 128;   // IN == HID
constexpr int ODIM = 64;    // NC
constexpr int NB   = 256;   // scan blocks per graph

// ---------------- column stats (deterministic two-stage) ----------------
template<int C>
__global__ void k_colstats(const float* __restrict__ X, int N, float* __restrict__ partial) {
    const int c = threadIdx.x;          // blockDim.x == C
    const int nb = gridDim.x;
    const int rows_per = (N + nb - 1) / nb;
    const int r0 = blockIdx.x * rows_per;
    const int r1 = min(N, r0 + rows_per);
    float s = 0.f, ss = 0.f;
    for (int r = r0; r < r1; ++r) {
        float v = X[(size_t)r * C + c];
        s += v;
        ss += v * v;
    }
    partial[(size_t)blockIdx.x * (2 * C) + c]     = s;
    partial[(size_t)blockIdx.x * (2 * C) + C + c] = ss;
}

template<int C>
__global__ void k_colstats_fin(const float* __restrict__ partial, int nb, int N,
                               const float* __restrict__ gamma, const float* __restrict__ beta,
                               float* __restrict__ scale, float* __restrict__ shift) {
    const int c = threadIdx.x;          // blockDim.x == C
    float s = 0.f, ss = 0.f;
    for (int b = 0; b < nb; ++b) {
        s  += partial[(size_t)b * (2 * C) + c];
        ss += partial[(size_t)b * (2 * C) + C + c];
    }
    const float mu  = s / (float)N;
    const float var = ss / (float)N - mu * mu;
    const float sc  = gamma[c] * rsqrtf(var + 1e-5f);
    scale[c] = sc;
    shift[c] = beta[c] - mu * sc;
}

// ---------------- degree (3 graphs, blockIdx.y) ----------------
__global__ void k_deg3(const int* __restrict__ d0, const int* __restrict__ d1,
                       const int* __restrict__ d2, int e0, int e1, int e2,
                       unsigned* __restrict__ deg, int N) {
    const int g = blockIdx.y;
    const int* dst = (g == 0) ? d0 : (g == 1) ? d1 : d2;
    const int E = (g == 0) ? e0 : (g == 1) ? e1 : e2;
    unsigned* dg = deg + (size_t)g * N;
    int i = blockIdx.x * blockDim.x + threadIdx.x;
    const int stride = gridDim.x * blockDim.x;
    for (; i < E; i += stride) atomicAdd(&dg[dst[i]], 1u);
}

// ---------------- parallel deterministic exclusive scan (3 kernels) ----------------
__global__ __launch_bounds__(256) void k_bsum(const unsigned* __restrict__ deg,
                                              unsigned* __restrict__ bsum, int N) {
    const int g = blockIdx.y, b = blockIdx.x, t = threadIdx.x;
    const unsigned* d = deg + (size_t)g * N;
    const int chunk = (N + gridDim.x - 1) / gridDim.x;
    const int i0 = b * chunk, i1 = min(N, i0 + chunk);
    unsigned s = 0;
    for (int i = i0 + t; i < i1; i += 256) s += d[i];
    __shared__ unsigned red[256];
    red[t] = s;
    __syncthreads();
    for (int ofs = 128; ofs; ofs >>= 1) {
        if (t < ofs) red[t] += red[t + ofs];
        __syncthreads();
    }
    if (t == 0) bsum[g * gridDim.x + b] = red[0];
}

__global__ void k_bscan(unsigned* __restrict__ bsum, int n) {
    const int t = threadIdx.x;
    __shared__ unsigned ps[3 * NB];
    unsigned v = (t < n) ? bsum[t] : 0u;
    ps[t] = v;
    __syncthreads();
    for (int ofs = 1; ofs < NB; ofs <<= 1) {
        const unsigned add = ((t & (NB - 1)) >= ofs) ? ps[t - ofs] : 0u;
        __syncthreads();
        ps[t] += add;
        __syncthreads();
    }
    if (t < n) bsum[t] = ps[t] - v;   // exclusive within each graph segment
}

__global__ __launch_bounds__(256) void k_scan2(const unsigned* __restrict__ deg,
                                               const unsigned* __restrict__ bofs,
                                               int* __restrict__ off, int* __restrict__ cur,
                                               float* __restrict__ rinv, int N) {
    const int g = blockIdx.y, b = blockIdx.x, t = threadIdx.x;
    const unsigned* d = deg + (size_t)g * N;
    int* o = off + (size_t)g * N;
    int* c = cur + (size_t)g * N;
    float* rv = rinv + (size_t)g * N;
    const int chunk = (N + gridDim.x - 1) / gridDim.x;
    const int i0 = b * chunk, i1 = min(N, i0 + chunk);
    unsigned run = bofs[g * gridDim.x + b];
    __shared__ unsigned ps[256];
    for (int base = i0; base < i1; base += 256) {
        const int i = base + t;
        const unsigned v = (i < i1) ? d[i] : 0u;
        ps[t] = v;
        __syncthreads();
        for (int ofs = 1; ofs < 256; ofs <<= 1) {
            const unsigned add = (t >= ofs) ? ps[t - ofs] : 0u;
            __syncthreads();
            ps[t] += add;
            __syncthreads();
        }
        if (i < i1) {
            const unsigned ex = run + ps[t] - v;
            o[i] = (int)ex;
            c[i] = (int)ex;
            rv[i] = 1.0f / ((float)v + 1.0f);
        }
        run += ps[255];
        __syncthreads();
    }
}

// ---------------- fill CSR neighbor lists (3 graphs, blockIdx.y) ----------------
__global__ void k_fill3(const int* __restrict__ s0, const int* __restrict__ d0,
                        const int* __restrict__ s1, const int* __restrict__ d1,
                        const int* __restrict__ s2, const int* __restrict__ d2,
                        int e0, int e1, int e2, int* __restrict__ cur,
                        int* __restrict__ n0, int* __restrict__ n1, int* __restrict__ n2,
                        int N) {
    const int g = blockIdx.y;
    const int* src = (g == 0) ? s0 : (g == 1) ? s1 : s2;
    const int* dst = (g == 0) ? d0 : (g == 1) ? d1 : d2;
    const int E = (g == 0) ? e0 : (g == 1) ? e1 : e2;
    int* nbr = (g == 0) ? n0 : (g == 1) ? n1 : n2;
    int* cu = cur + (size_t)g * N;
    int i = blockIdx.x * blockDim.x + threadIdx.x;
    const int stride = gridDim.x * blockDim.x;
    for (; i < E; i += stride) {
        const int v = dst[i];
        const int p = atomicAdd(&cu[v], 1);
        nbr[p] = src[i];
    }
}

// ---------------- gather (128-dim), BN1 fused: AGG[v] = s1*(rinv*S_raw) + sh1 ----------------
__global__ __launch_bounds__(256) void k_gather128(
    const float* __restrict__ X, const int* __restrict__ nbr,
    const int* __restrict__ off, const int* __restrict__ cend,
    const float* __restrict__ rinv, const float* __restrict__ s1,
    const float* __restrict__ sh1, float* __restrict__ AGG, int N) {
    const int wave = threadIdx.x >> 6;
    const int lane = threadIdx.x & 63;
    const int v = blockIdx.x * 4 + wave;
    if (v >= N) return;
    const int i0 = off[v], i1 = cend[v];
    const int l2 = lane * 2;
    float2 acc = *(const float2*)&X[(size_t)v * FDIM + l2];   // self (raw x)
    int i = i0;
    for (; i + 8 <= i1; i += 8) {
        const int u0 = nbr[i],     u1 = nbr[i + 1], u2 = nbr[i + 2], u3 = nbr[i + 3];
        const int u4 = nbr[i + 4], u5 = nbr[i + 5], u6 = nbr[i + 6], u7 = nbr[i + 7];
        const float2 a0 = *(const float2*)&X[(size_t)u0 * FDIM + l2];
        const float2 a1 = *(const float2*)&X[(size_t)u1 * FDIM + l2];
        const float2 a2 = *(const float2*)&X[(size_t)u2 * FDIM + l2];
        const float2 a3 = *(const float2*)&X[(size_t)u3 * FDIM + l2];
        const float2 a4 = *(const float2*)&X[(size_t)u4 * FDIM + l2];
        const float2 a5 = *(const float2*)&X[(size_t)u5 * FDIM + l2];
        const float2 a6 = *(const float2*)&X[(size_t)u6 * FDIM + l2];
        const float2 a7 = *(const float2*)&X[(size_t)u7 * FDIM + l2];
        acc.x += ((a0.x + a1.x) + (a2.x + a3.x)) + ((a4.x + a5.x) + (a6.x + a7.x));
        acc.y += ((a0.y + a1.y) + (a2.y + a3.y)) + ((a4.y + a5.y) + (a6.y + a7.y));
    }
    for (; i < i1; ++i) {
        const int u = nbr[i];
        const float2 a = *(const float2*)&X[(size_t)u * FDIM + l2];
        acc.x += a.x;
        acc.y += a.y;
    }
    const float r = rinv[v];
    const float2 sc = *(const float2*)&s1[l2];
    const float2 sh = *(const float2*)&sh1[l2];
    float2 o;
    o.x = fmaf(acc.x * r, sc.x, sh.x);
    o.y = fmaf(acc.y * r, sc.y, sh.y);
    *(float2*)&AGG[(size_t)v * FDIM + l2] = o;
}

// ---------------- GEMM accumulate: H (+)= A @ W, 64x128 block ----------------
template<bool INIT, bool RELU>
__global__ __launch_bounds__(256) void k_gemm_acc(
    const float* __restrict__ A, const float* __restrict__ W,
    const float* __restrict__ b1, const float* __restrict__ b2, const float* __restrict__ b3,
    float* __restrict__ H, int N) {
    __shared__ float At[16][64];
    __shared__ float Bt[16][128];
    const int t = threadIdx.x;
    const int row0 = blockIdx.x * 64;
    const int c0 = (t & 31) * 4;     // 0..124
    const int r0 = (t >> 5) * 8;     // 0..56
    float acc[8][4];
    #pragma unroll
    for (int r = 0; r < 8; ++r)
        #pragma unroll
        for (int c = 0; c < 4; ++c) acc[r][c] = 0.f;

    for (int kb = 0; kb < 8; ++kb) {       // K = 128
        const int k0 = kb * 16;
        {
            const int kk = t & 15;
            const int rb = t >> 4;          // 0..15
            #pragma unroll
            for (int it = 0; it < 4; ++it) {
                const int r = rb + it * 16;
                const int row = row0 + r;
                At[kk][r] = (row < N) ? A[(size_t)row * FDIM + k0 + kk] : 0.f;
            }
        }
        {
            const int n = t & 127;
            const int kkb = t >> 7;         // 0..1
            #pragma unroll
            for (int it = 0; it < 8; ++it) {
                const int kk = kkb + it * 2;
                Bt[kk][n] = W[(size_t)(k0 + kk) * 128 + n];
            }
        }
        __syncthreads();
        #pragma unroll
        for (int kk = 0; kk < 16; ++kk) {
            const float4 b  = *(const float4*)&Bt[kk][c0];
            const float4 a0 = *(const float4*)&At[kk][r0];
            const float4 a1 = *(const float4*)&At[kk][r0 + 4];
            const float a[8] = {a0.x, a0.y, a0.z, a0.w, a1.x, a1.y, a1.z, a1.w};
            #pragma unroll
            for (int r = 0; r < 8; ++r) {
                acc[r][0] = fmaf(a[r], b.x, acc[r][0]);
                acc[r][1] = fmaf(a[r], b.y, acc[r][1]);
                acc[r][2] = fmaf(a[r], b.z, acc[r][2]);
                acc[r][3] = fmaf(a[r], b.w, acc[r][3]);
            }
        }
        __syncthreads();
    }
    float4 base;
    if (INIT) {
        base.x = b1[c0 + 0] + b2[c0 + 0] + b3[c0 + 0];
        base.y = b1[c0 + 1] + b2[c0 + 1] + b3[c0 + 1];
        base.z = b1[c0 + 2] + b2[c0 + 2] + b3[c0 + 2];
        base.w = b1[c0 + 3] + b2[c0 + 3] + b3[c0 + 3];
    }
    #pragma unroll
    for (int r = 0; r < 8; ++r) {
        const int row = row0 + r0 + r;
        if (row < N) {
            float4 o;
            float4 prev;
            if (!INIT) prev = *(const float4*)&H[(size_t)row * FDIM + c0];
            o.x = acc[r][0] + (INIT ? base.x : prev.x);
            o.y = acc[r][1] + (INIT ? base.y : prev.y);
            o.z = acc[r][2] + (INIT ? base.z : prev.z);
            o.w = acc[r][3] + (INIT ? base.w : prev.w);
            if (RELU) {
                o.x = fmaxf(o.x, 0.f); o.y = fmaxf(o.y, 0.f);
                o.z = fmaxf(o.z, 0.f); o.w = fmaxf(o.w, 0.f);
            }
            *(float4*)&H[(size_t)row * FDIM + c0] = o;
        }
    }
}

// ---------------- c2[g][n] = sum_k sh2[k] * Wg[k][n] (BN2 shift folded through GEMM2) ----------------
__global__ void k_c2(const float* __restrict__ sh2,
                     const float* __restrict__ W1, const float* __restrict__ W2,
                     const float* __restrict__ W3, float* __restrict__ c2) {
    const int t = threadIdx.x;   // 192
    const int g = t >> 6, n = t & 63;
    const float* W = (g == 0) ? W1 : (g == 1) ? W2 : W3;
    float s = 0.f;
    for (int k = 0; k < 128; ++k) s = fmaf(sh2[k], W[(size_t)k * ODIM + n], s);
    c2[g * ODIM + n] = s;
}

// ---------------- GEMM2 (BN2 scale fused into A-load): U_g = (H*s2) @ W_g2 + c2_g ----------------
__global__ __launch_bounds__(256) void k_gemm2(
    const float* __restrict__ H, const float* __restrict__ s2,
    const float* __restrict__ W1, const float* __restrict__ W2, const float* __restrict__ W3,
    const float* __restrict__ c2, float* __restrict__ U, int N) {
    __shared__ float At[16][64];
    __shared__ float Bt[16][64];
    const int t = threadIdx.x;
    const int g = blockIdx.y;
    const int row0 = blockIdx.x * 64;
    const int c0 = (t & 15) * 4;     // 0..60
    const int r0 = (t >> 4) * 4;     // 0..60
    const float* Wg = (g == 0) ? W1 : (g == 1) ? W2 : W3;
    float acc[4][4];
    #pragma unroll
    for (int r = 0; r < 4; ++r)
        #pragma unroll
        for (int c = 0; c < 4; ++c) acc[r][c] = 0.f;

    for (int kb = 0; kb < 8; ++kb) {       // K = 128
        const int k0 = kb * 16;
        {
            const int kk = t & 15;
            const int rb = t >> 4;          // 0..15
            const float sv = s2[k0 + kk];
            #pragma unroll
            for (int it = 0; it < 4; ++it) {
                const int r = rb + it * 16;
                const int row = row0 + r;
                At[kk][r] = (row < N) ? H[(size_t)row * FDIM + k0 + kk] * sv : 0.f;
            }
        }
        {
            const int n = t & 63;
            const int kkb = t >> 6;         // 0..3
            #pragma unroll
            for (int it = 0; it < 4; ++it) {
                const int kk = kkb + it * 4;
                Bt[kk][n] = Wg[(size_t)(k0 + kk) * ODIM + n];
            }
        }
        __syncthreads();
        #pragma unroll
        for (int kk = 0; kk < 16; ++kk) {
            const float4 b = *(const float4*)&Bt[kk][c0];
            const float4 a = *(const float4*)&At[kk][r0];
            const float av[4] = {a.x, a.y, a.z, a.w};
            #pragma unroll
            for (int r = 0; r < 4; ++r) {
                acc[r][0] = fmaf(av[r], b.x, acc[r][0]);
                acc[r][1] = fmaf(av[r], b.y, acc[r][1]);
                acc[r][2] = fmaf(av[r], b.z, acc[r][2]);
                acc[r][3] = fmaf(av[r], b.w, acc[r][3]);
            }
        }
        __syncthreads();
    }
    const float* cg = c2 + (size_t)g * ODIM;
    float* Ug = U + (size_t)g * N * ODIM;
    #pragma unroll
    for (int r = 0; r < 4; ++r) {
        const int row = row0 + r0 + r;
        if (row < N) {
            float4 o;
            o.x = acc[r][0] + cg[c0 + 0];
            o.y = acc[r][1] + cg[c0 + 1];
            o.z = acc[r][2] + cg[c0 + 2];
            o.w = acc[r][3] + cg[c0 + 3];
            *(float4*)&Ug[(size_t)row * ODIM + c0] = o;
        }
    }
}

// ---------------- layer-2 gather + combine ----------------
__global__ __launch_bounds__(256) void k_gc64(
    const float* __restrict__ U,
    const int* __restrict__ nbr0, const int* __restrict__ nbr1, const int* __restrict__ nbr2,
    const int* __restrict__ off, const int* __restrict__ cend,
    const float* __restrict__ rinv,
    const float* __restrict__ b1, const float* __restrict__ b2, const float* __restrict__ b3,
    float* __restrict__ Z, int N) {
    const int wave = threadIdx.x >> 6;
    const int lane = threadIdx.x & 63;
    const int v = blockIdx.x * 4 + wave;
    if (v >= N) return;
    const size_t gs = (size_t)N * ODIM;
    float z = b1[lane] + b2[lane] + b3[lane];
    #pragma unroll
    for (int g = 0; g < 3; ++g) {
        const float* Ug = U + (size_t)g * gs;
        const int* nb = (g == 0) ? nbr0 : (g == 1) ? nbr1 : nbr2;
        const int i0 = off[g * N + v], i1 = cend[g * N + v];
        float s = Ug[(size_t)v * ODIM + lane];
        int i = i0;
        for (; i + 8 <= i1; i += 8) {
            const int u0 = nb[i],     u1 = nb[i + 1], u2 = nb[i + 2], u3 = nb[i + 3];
            const int u4 = nb[i + 4], u5 = nb[i + 5], u6 = nb[i + 6], u7 = nb[i + 7];
            const float a0 = Ug[(size_t)u0 * ODIM + lane];
            const float a1 = Ug[(size_t)u1 * ODIM + lane];
            const float a2 = Ug[(size_t)u2 * ODIM + lane];
            const float a3 = Ug[(size_t)u3 * ODIM + lane];
            const float a4 = Ug[(size_t)u4 * ODIM + lane];
            const float a5 = Ug[(size_t)u5 * ODIM + lane];
            const float a6 = Ug[(size_t)u6 * ODIM + lane];
            const float a7 = Ug[(size_t)u7 * ODIM + lane];
            s += ((a0 + a1) + (a2 + a3)) + ((a4 + a5) + (a6 + a7));
        }
        for (; i < i1; ++i) s += Ug[(size_t)nb[i] * ODIM + lane];
        z += s * rinv[g * N + v];
    }
    Z[(size_t)v * ODIM + lane] = z;
}

// ---------------- final: BN3 + sigmoid + row min-max + row L2, in place ----------------
__global__ __launch_bounds__(256) void k_final(float* __restrict__ Z,
                                               const float* __restrict__ scale,
                                               const float* __restrict__ shift, int N) {
    const int wave = threadIdx.x >> 6;
    const int lane = threadIdx.x & 63;
    const int row = blockIdx.x * 4 + wave;
    if (row >= N) return;
    float v = fmaf(Z[(size_t)row * ODIM + lane], scale[lane], shift[lane]);
    float s = 1.0f / (1.0f + expf(-v));
    float mn = s, mx = s;
    #pragma unroll
    for (int off = 32; off; off >>= 1) {
        mn = fminf(mn, __shfl_xor(mn, off, 64));
        mx = fmaxf(mx, __shfl_xor(mx, off, 64));
    }
    const float sc = (s - mn) / (mx - mn);
    float sq = sc * sc;
    #pragma unroll
    for (int off = 32; off; off >>= 1) sq += __shfl_xor(sq, off, 64);
    const float norm = fmaxf(sqrtf(sq), 1e-12f);
    Z[(size_t)row * ODIM + lane] = sc / norm;
}

extern "C" void kernel_launch(void* const* d_in, const int* in_sizes, int n_in,
                              void* d_out, int out_size, void* d_ws, size_t ws_size,
                              hipStream_t stream) {
    const float* x = (const float*)d_in[0];
    const int* src[3] = {(const int*)d_in[1], (const int*)d_in[3], (const int*)d_in[5]};
    const int* dst[3] = {(const int*)d_in[2], (const int*)d_in[4], (const int*)d_in[6]};
    const int E[3] = {in_sizes[1], in_sizes[3], in_sizes[5]};
    const float* W11 = (const float*)d_in[7];  const float* b11 = (const float*)d_in[8];
    const float* W21 = (const float*)d_in[9];  const float* b21 = (const float*)d_in[10];
    const float* W31 = (const float*)d_in[11]; const float* b31 = (const float*)d_in[12];
    const float* W12 = (const float*)d_in[13]; const float* b12 = (const float*)d_in[14];
    const float* W22 = (const float*)d_in[15]; const float* b22 = (const float*)d_in[16];
    const float* W32 = (const float*)d_in[17]; const float* b32 = (const float*)d_in[18];
    const float* g1  = (const float*)d_in[19]; const float* be1 = (const float*)d_in[20];
    const float* g2  = (const float*)d_in[21]; const float* be2 = (const float*)d_in[22];
    const float* g3  = (const float*)d_in[23]; const float* be3 = (const float*)d_in[24];
    const int N = in_sizes[0] / FDIM;
    float* Z = (float*)d_out;

    // ---- workspace layout (floats) ----
    float* ws   = (float*)d_ws;
    float* AGG  = ws;                          // N*128 (25.6 MB), per-graph scratch
    float* H    = AGG + (size_t)N * FDIM;      // N*128 (25.6 MB)
    float* U    = H + (size_t)N * FDIM;        // 3*N*64 (38.4 MB)
    float* rinv = U + (size_t)3 * N * ODIM;    // 3N
    float* partial = rinv + (size_t)3 * N;     // 65536
    float* s1  = partial + 65536;  float* sh1 = s1 + 128;
    float* s2  = sh1 + 128;        float* sh2 = s2 + 128;
    float* s3  = sh2 + 128;        float* sh3 = s3 + 64;
    float* c2  = sh3 + 64;                     // 3*64
    // int region
    unsigned* degi  = (unsigned*)(c2 + 3 * ODIM);         // 3N
    unsigned* bsum  = degi + (size_t)3 * N;               // 3*NB
    int* off  = (int*)(bsum + (size_t)3 * NB);            // 3N
    int* cur  = off + (size_t)3 * N;                      // 3N
    int* nbr  = cur + (size_t)3 * N;                      // E0+E1+E2
    int* nbrg[3];
    nbrg[0] = nbr;
    nbrg[1] = nbrg[0] + E[0];
    nbrg[2] = nbrg[1] + E[1];

    // ---- degrees + CSR build ----
    hipMemsetAsync(degi, 0, (size_t)3 * N * sizeof(unsigned), stream);
    k_deg3<<<dim3(512, 3), 256, 0, stream>>>(dst[0], dst[1], dst[2], E[0], E[1], E[2], degi, N);
    k_bsum<<<dim3(NB, 3), 256, 0, stream>>>(degi, bsum, N);
    k_bscan<<<1, 3 * NB, 0, stream>>>(bsum, 3 * NB);
    k_scan2<<<dim3(NB, 3), 256, 0, stream>>>(degi, bsum, off, cur, rinv, N);
    k_fill3<<<dim3(768, 3), 256, 0, stream>>>(src[0], dst[0], src[1], dst[1], src[2], dst[2],
                                              E[0], E[1], E[2], cur,
                                              nbrg[0], nbrg[1], nbrg[2], N);

    // ---- BN1 stats (applied inside gather epilogue) ----
    k_colstats<128><<<256, 128, 0, stream>>>(x, N, partial);
    k_colstats_fin<128><<<1, 128, 0, stream>>>(partial, 256, N, g1, be1, s1, sh1);

    // ---- layer 1: per-graph gather (BN1 fused) -> accumulate GEMM ----
    const int gblocks = (N + 3) / 4;
    k_gather128<<<gblocks, 256, 0, stream>>>(x, nbrg[0], off, cur, rinv, s1, sh1, AGG, N);
    k_gemm_acc<true, false><<<(N + 63) / 64, 256, 0, stream>>>(AGG, W11, b11, b21, b31, H, N);
    k_gather128<<<gblocks, 256, 0, stream>>>(x, nbrg[1], off + N, cur + N, rinv + N, s1, sh1, AGG, N);
    k_gemm_acc<false, false><<<(N + 63) / 64, 256, 0, stream>>>(AGG, W21, b11, b21, b31, H, N);
    k_gather128<<<gblocks, 256, 0, stream>>>(x, nbrg[2], off + 2 * N, cur + 2 * N, rinv + 2 * N, s1, sh1, AGG, N);
    k_gemm_acc<false, true><<<(N + 63) / 64, 256, 0, stream>>>(AGG, W31, b11, b21, b31, H, N);

    // ---- BN2 stats (scale fused into GEMM2 A-load, shift folded via c2) ----
    k_colstats<128><<<256, 128, 0, stream>>>(H, N, partial);
    k_colstats_fin<128><<<1, 128, 0, stream>>>(partial, 256, N, g2, be2, s2, sh2);
    k_c2<<<1, 192, 0, stream>>>(sh2, W12, W22, W32, c2);

    // ---- layer 2: GEMM first (linearity), then fused gather+combine ----
    dim3 grid2((N + 63) / 64, 3);
    k_gemm2<<<grid2, 256, 0, stream>>>(H, s2, W12, W22, W32, c2, U, N);
    k_gc64<<<gblocks, 256, 0, stream>>>(U, nbrg[0], nbrg[1], nbrg[2], off, cur, rinv,
                                        b12, b22, b32, Z, N);

    // ---- BN3 + epilogue ----
    k_colstats<64><<<256, 64, 0, stream>>>(Z, N, partial);
    k_colstats_fin<64><<<1, 64, 0, stream>>>(partial, 256, N, g3, be3, s3, sh3);
    k_final<<<(N + 3) / 4, 256, 0, stream>>>(Z, s3, sh3, N);
}